// Round 18
// baseline (468.314 us; speedup 1.0000x reference)
//
#include <hip/hip_runtime.h>
#include <hip/hip_bf16.h>

namespace {

constexpr int NN = 20000;   // nodes
constexpr int NE = 320000;  // edges
constexpr int DI = 64;      // input node dim
constexpr int DE = 16;      // edge attr dim
constexpr int DM = 256;     // hidden dim
constexpr int DO = 10;      // out dim

__host__ __device__ constexpr size_t woff(int m) {
  return m == 0 ? 0 : (size_t)16384 + (size_t)(m - 1) * 65536;
}
constexpr size_t WTOTAL = 16384 + 11 * 65536;

typedef __attribute__((ext_vector_type(8))) short s16x8;
typedef __attribute__((ext_vector_type(4))) float f32x4;
typedef __attribute__((ext_vector_type(2))) float f32x2;

#if __has_builtin(__builtin_amdgcn_cvt_pk_f32_fp8) && __has_builtin(__builtin_amdgcn_cvt_pk_fp8_f32)
#define HWFP8 1
#else
#define HWFP8 0
#endif

__device__ inline unsigned short f2bf(float x) {
  union { float f; unsigned u; } c; c.f = x;
  unsigned r = (c.u + 0x7FFFu + ((c.u >> 16) & 1u)) >> 16;
  return (unsigned short)r;
}
__device__ inline float bf2f(unsigned short h) {
  union { unsigned u; float f; } c; c.u = ((unsigned)h) << 16;
  return c.f;
}

#if HWFP8
__device__ inline void dec8(unsigned lo, unsigned hi, float* e) {
  const f32x2 d0 = __builtin_amdgcn_cvt_pk_f32_fp8((int)lo, false);
  const f32x2 d1 = __builtin_amdgcn_cvt_pk_f32_fp8((int)lo, true);
  const f32x2 d2 = __builtin_amdgcn_cvt_pk_f32_fp8((int)hi, false);
  const f32x2 d3 = __builtin_amdgcn_cvt_pk_f32_fp8((int)hi, true);
  e[0] = d0.x; e[1] = d0.y; e[2] = d1.x; e[3] = d1.y;
  e[4] = d2.x; e[5] = d2.y; e[6] = d3.x; e[7] = d3.y;
}
#else
// software pair: extended-normal-at-e0 encode + matching decode
__device__ inline unsigned char f2e4m3(float x) {
  union { float f; unsigned u; } c; c.f = x;
  const unsigned s = (c.u >> 24) & 0x80u;
  c.u &= 0x7FFFFFFFu;
  c.f = fminf(c.f, 448.f);
  const unsigned b = c.u + 0x7FFFFu + ((c.u >> 20) & 1u);
  unsigned r = (b >> 20) - 960u;
  r = (c.f >= 0.0078125f) ? r : 0u;
  return (unsigned char)(s | r);
}
__device__ inline float e4m32f(unsigned u) {
  unsigned b = ((u & 0x80u) << 24) | (((u & 0x7Fu) << 20) + 0x3C000000u);
  if ((u & 0x7Fu) == 0) b &= 0x80000000u;
  union { unsigned u; float f; } c; c.u = b;
  return c.f;
}
__device__ inline void dec8(unsigned lo, unsigned hi, float* e) {
  #pragma unroll
  for (int k = 0; k < 4; ++k) {
    e[k]     = e4m32f((lo >> (8 * k)) & 255u);
    e[4 + k] = e4m32f((hi >> (8 * k)) & 255u);
  }
}
#endif

// ---------------- CSR build (counting sort by dst) ----------------

__global__ __launch_bounds__(256) void zero_kernel(int* __restrict__ p, int n) {
  const int j = blockIdx.x * 256 + threadIdx.x;
  if (j < n) p[j] = 0;
}

__global__ __launch_bounds__(256) void hist_kernel(
    const int* __restrict__ dst, int* __restrict__ counts, int E)
{
  const int j = blockIdx.x * 256 + threadIdx.x;
  if (j < E) atomicAdd(&counts[dst[j]], 1);
}

__global__ __launch_bounds__(1024) void scan_kernel(
    const int* __restrict__ counts, int* __restrict__ row_ptr,
    int* __restrict__ cursor, int n)
{
  __shared__ int partial[1024];
  const int t = threadIdx.x;
  const int chunk = (n + 1023) / 1024;
  const int beg = t * chunk;
  const int end = min(beg + chunk, n);
  int s = 0;
  for (int i = beg; i < end; ++i) s += counts[i];
  partial[t] = s;
  __syncthreads();
  for (int off = 1; off < 1024; off <<= 1) {
    const int v = (t >= off) ? partial[t - off] : 0;
    __syncthreads();
    partial[t] += v;
    __syncthreads();
  }
  int base = (t == 0) ? 0 : partial[t - 1];
  for (int i = beg; i < end; ++i) {
    const int c = counts[i];
    row_ptr[i] = base;
    cursor[i] = base;
    base += c;
  }
  if (t == 1023) row_ptr[n] = partial[1023];
}

__global__ __launch_bounds__(256) void scatter_kernel(
    const int* __restrict__ src, const int* __restrict__ dst,
    const float* __restrict__ eattr, int* __restrict__ cursor,
    int* __restrict__ esrc, unsigned short* __restrict__ ea16, int E)
{
  const int j = blockIdx.x * 256 + threadIdx.x;
  if (j < E) {
    const int p = atomicAdd(&cursor[dst[j]], 1);
    esrc[p] = src[j];
    const float4* ep = reinterpret_cast<const float4*>(&eattr[(size_t)j * DE]);
    const float4 e0 = ep[0], e1 = ep[1], e2 = ep[2], e3 = ep[3];
    const float ea[16] = {e0.x, e0.y, e0.z, e0.w, e1.x, e1.y, e1.z, e1.w,
                          e2.x, e2.y, e2.z, e2.w, e3.x, e3.y, e3.z, e3.w};
    s16x8 v0, v1;
    #pragma unroll
    for (int k = 0; k < 8; ++k) {
      v0[k] = (short)f2bf(ea[k]);
      v1[k] = (short)f2bf(ea[8 + k]);
    }
    s16x8* op = reinterpret_cast<s16x8*>(&ea16[(size_t)p * DE]);
    op[0] = v0; op[1] = v1;
  }
}

// ---------------- weight preprocessing: transpose + bf16 ----------------
// mat 0..11 = main weights; mat 12 = W_ee (16x256 -> 256x16)
__global__ __launch_bounds__(256) void convertW_kernel(
    const float* __restrict__ W_ne, const float* __restrict__ W_pre,
    const float* __restrict__ W1_a, const float* __restrict__ W2_a,
    const float* __restrict__ W1_l, const float* __restrict__ W2_l,
    const float* __restrict__ Wee,
    unsigned short* __restrict__ hi, unsigned short* __restrict__ Wt16)
{
  const int mat = blockIdx.y;
  if (mat == 12) {
    if (blockIdx.x == 0) {
      const int n = threadIdx.x;
      #pragma unroll
      for (int k = 0; k < DE; ++k)
        Wt16[n * DE + k] = f2bf(Wee[k * DM + n]);
    }
    return;
  }
  const float* src;
  int K = 256;
  if (mat == 0)      { src = W_ne;  K = 64; }
  else if (mat == 1) { src = W_pre; }
  else if (mat == 2) { src = W1_a; }
  else if (mat == 3) { src = W2_a; }
  else if (mat < 8)  { src = W1_l + (size_t)(mat - 4) * 65536; }
  else               { src = W2_l + (size_t)(mat - 8) * 65536; }
  const size_t off = woff(mat);

  const int ntiles = (K >> 6) * 4;
  const int t = blockIdx.x;
  if (t >= ntiles) return;
  const int tk = t % (K >> 6);
  const int tn = t / (K >> 6);

  __shared__ float tile[64][65];
  const int tid = threadIdx.x;
  const int c = tid & 63;
  const int rg = tid >> 6;
  for (int i = 0; i < 16; ++i) {
    const int r = rg + i * 4;
    tile[r][c] = src[(size_t)(tk * 64 + r) * 256 + tn * 64 + c];
  }
  __syncthreads();
  const int k = tk * 64 + c;
  for (int i = 0; i < 16; ++i) {
    const int nn = rg + i * 4;
    const int n = tn * 64 + nn;
    hi[off + (size_t)n * K + k] = f2bf(tile[c][nn]);
  }
}

// ---------------- edge encoder: e8[p] = e4m3(ea16[p] @ W_ee + b_ee) -----
__global__ __launch_bounds__(256) void eenc_kernel(
    const unsigned short* __restrict__ ea16, const unsigned short* __restrict__ Wt16,
    const float* __restrict__ bee, unsigned char* __restrict__ e8)
{
  __shared__ unsigned stage_dw[128][36];  // 144 B/row
  const int tid = threadIdx.x;
  const int lane = tid & 63, wid = tid >> 6;
  const int l15 = lane & 15, l4 = lane >> 4;
  const int eBase0 = blockIdx.x * 128;
  const int eBase = eBase0 + wid * 32;
  const int colBase = blockIdx.y * 128;
  const s16x8 zz = {0, 0, 0, 0, 0, 0, 0, 0};

  s16x8 ah[2];
  #pragma unroll
  for (int mi = 0; mi < 2; ++mi) {
    const int edge = eBase + mi * 16 + l15;
    ah[mi] = (l4 < 2)
        ? *reinterpret_cast<const s16x8*>(&ea16[(size_t)edge * DE + l4 * 8]) : zz;
  }
  s16x8 bh[8];
  #pragma unroll
  for (int ni = 0; ni < 8; ++ni) {
    const int col = colBase + ni * 16 + l15;
    bh[ni] = (l4 < 2)
        ? *reinterpret_cast<const s16x8*>(&Wt16[col * DE + l4 * 8]) : zz;
  }
  f32x4 acc2[8][2];
  #pragma unroll
  for (int ni = 0; ni < 8; ++ni)
    #pragma unroll
    for (int mi = 0; mi < 2; ++mi)
      acc2[ni][mi] = (f32x4){0.f, 0.f, 0.f, 0.f};
  #pragma unroll
  for (int ni = 0; ni < 8; ++ni)
    #pragma unroll
    for (int mi = 0; mi < 2; ++mi)
      acc2[ni][mi] = __builtin_amdgcn_mfma_f32_16x16x32_bf16(bh[ni], ah[mi], acc2[ni][mi], 0, 0, 0);

  #pragma unroll
  for (int ni = 0; ni < 8; ++ni) {
    const float4 bv = *reinterpret_cast<const float4*>(&bee[colBase + ni * 16 + l4 * 4]);
    #pragma unroll
    for (int mi = 0; mi < 2; ++mi) {
      const int erow = wid * 32 + mi * 16 + l15;
      const float v0 = acc2[ni][mi][0] + bv.x;
      const float v1 = acc2[ni][mi][1] + bv.y;
      const float v2 = acc2[ni][mi][2] + bv.z;
      const float v3 = acc2[ni][mi][3] + bv.w;
#if HWFP8
      unsigned dw = 0;
      dw = (unsigned)__builtin_amdgcn_cvt_pk_fp8_f32(v0, v1, (int)dw, false);
      dw = (unsigned)__builtin_amdgcn_cvt_pk_fp8_f32(v2, v3, (int)dw, true);
      stage_dw[erow][ni * 4 + l4] = dw;
#else
      unsigned char* bp = reinterpret_cast<unsigned char*>(&stage_dw[erow][0]);
      const int col0 = ni * 16 + l4 * 4;
      bp[col0 + 0] = f2e4m3(v0); bp[col0 + 1] = f2e4m3(v1);
      bp[col0 + 2] = f2e4m3(v2); bp[col0 + 3] = f2e4m3(v3);
#endif
    }
  }
  __syncthreads();
  const unsigned char* sb = reinterpret_cast<const unsigned char*>(stage_dw);
  #pragma unroll
  for (int it = 0; it < 4; ++it) {
    const int idx = tid + it * 256;
    const int e = idx >> 3, cc = idx & 7;
    const s16x8 v = *reinterpret_cast<const s16x8*>(sb + (size_t)e * 144 + cc * 16);
    *reinterpret_cast<s16x8*>(&e8[(size_t)(eBase0 + e) * DM + colBase + cc * 16]) = v;
  }
}

// ---------------- fused MLP: BM=64, 512 threads, bf16 weights --------
template<bool RELU1, bool RELU2, bool RESID, bool ABF16>
__global__ __launch_bounds__(512) void mlp_kernel(
    const float* __restrict__ Af, const unsigned short* __restrict__ Ab,
    const unsigned short* __restrict__ B1, const float* __restrict__ b1,
    const unsigned short* __restrict__ B2, const float* __restrict__ b2,
    unsigned short* __restrict__ O16, int M, int K1)
{
  __shared__ unsigned short Tst[64 * 256];
  __shared__ unsigned short Ws[256 * 32];
  unsigned short* Ast = Tst;

  const int tid = threadIdx.x;
  const int lane = tid & 63, wid = tid >> 6;
  const int wr = wid >> 2, wc = wid & 3;
  const int l15 = lane & 15, l4 = lane >> 4;
  const int rowBase = blockIdx.x * 64;
  const int colW = wc * 64;

  f32x4 acc[2][4];
  #pragma unroll
  for (int i = 0; i < 2; ++i)
    #pragma unroll
    for (int j = 0; j < 4; ++j) acc[i][j] = (f32x4){0.f, 0.f, 0.f, 0.f};

  const int nk1 = K1 >> 5;
  for (int ks = 0; ks < nk1; ++ks) {
    if (tid < 256) {
      const int row = tid >> 2, kc = tid & 3;
      const int grow = rowBase + row;
      const int chunk = row * 4 + (kc ^ (row & 3));
      s16x8 v = {0, 0, 0, 0, 0, 0, 0, 0};
      if (grow < M) {
        if (ABF16) {
          v = *reinterpret_cast<const s16x8*>(&Ab[(size_t)grow * K1 + ks * 32 + kc * 8]);
        } else {
          const float* p = Af + (size_t)grow * K1 + ks * 32 + kc * 8;
          const float4 v0 = *reinterpret_cast<const float4*>(p);
          const float4 v1 = *reinterpret_cast<const float4*>(p + 4);
          const float xs[8] = {v0.x, v0.y, v0.z, v0.w, v1.x, v1.y, v1.z, v1.w};
          #pragma unroll
          for (int j = 0; j < 8; ++j) v[j] = (short)f2bf(xs[j]);
        }
      }
      ((s16x8*)Ast)[chunk] = v;
    }
    #pragma unroll
    for (int i = 0; i < 2; ++i) {
      const int u = tid + i * 512;
      const int c = u >> 2, kc = u & 3;
      const int chunk = c * 4 + (kc ^ (c & 3));
      ((s16x8*)Ws)[chunk] = *reinterpret_cast<const s16x8*>(B1 + (size_t)c * K1 + ks * 32 + kc * 8);
    }
    __syncthreads();
    s16x8 a[2], bw[4];
    #pragma unroll
    for (int mi = 0; mi < 2; ++mi) {
      const int r = wr * 32 + mi * 16 + l15;
      a[mi] = ((const s16x8*)Ast)[r * 4 + (l4 ^ (r & 3))];
    }
    #pragma unroll
    for (int ni = 0; ni < 4; ++ni) {
      const int c = colW + ni * 16 + l15;
      bw[ni] = ((const s16x8*)Ws)[c * 4 + (l4 ^ (c & 3))];
    }
    #pragma unroll
    for (int mi = 0; mi < 2; ++mi)
      #pragma unroll
      for (int ni = 0; ni < 4; ++ni)
        acc[mi][ni] = __builtin_amdgcn_mfma_f32_16x16x32_bf16(a[mi], bw[ni], acc[mi][ni], 0, 0, 0);
    __syncthreads();
  }
  #pragma unroll
  for (int ni = 0; ni < 4; ++ni) {
    const int col = colW + ni * 16 + l15;
    const float bv = b1[col];
    #pragma unroll
    for (int mi = 0; mi < 2; ++mi) {
      #pragma unroll
      for (int r = 0; r < 4; ++r) {
        const int row = wr * 32 + mi * 16 + l4 * 4 + r;
        float v = acc[mi][ni][r] + bv;
        if (RELU1) v = fmaxf(v, 0.f);
        const int c32 = col >> 3;
        const int chunk = row * 32 + (c32 ^ (row & 31));
        Tst[chunk * 8 + (col & 7)] = f2bf(v);
        acc[mi][ni][r] = 0.f;
      }
    }
  }
  __syncthreads();

  for (int ks = 0; ks < 8; ++ks) {
    #pragma unroll
    for (int i = 0; i < 2; ++i) {
      const int u = tid + i * 512;
      const int c = u >> 2, kc = u & 3;
      const int chunk = c * 4 + (kc ^ (c & 3));
      ((s16x8*)Ws)[chunk] = *reinterpret_cast<const s16x8*>(B2 + (size_t)c * 256 + ks * 32 + kc * 8);
    }
    __syncthreads();
    s16x8 a[2], bw[4];
    #pragma unroll
    for (int mi = 0; mi < 2; ++mi) {
      const int row = wr * 32 + mi * 16 + l15;
      const int c32 = ks * 4 + l4;
      a[mi] = ((const s16x8*)Tst)[row * 32 + (c32 ^ (row & 31))];
    }
    #pragma unroll
    for (int ni = 0; ni < 4; ++ni) {
      const int c = colW + ni * 16 + l15;
      bw[ni] = ((const s16x8*)Ws)[c * 4 + (l4 ^ (c & 3))];
    }
    #pragma unroll
    for (int mi = 0; mi < 2; ++mi)
      #pragma unroll
      for (int ni = 0; ni < 4; ++ni)
        acc[mi][ni] = __builtin_amdgcn_mfma_f32_16x16x32_bf16(a[mi], bw[ni], acc[mi][ni], 0, 0, 0);
    __syncthreads();
  }
  #pragma unroll
  for (int ni = 0; ni < 4; ++ni) {
    const int gcol = colW + ni * 16 + l15;
    const float bv = b2[gcol];
    #pragma unroll
    for (int mi = 0; mi < 2; ++mi) {
      #pragma unroll
      for (int r = 0; r < 4; ++r) {
        const int grow = rowBase + wr * 32 + mi * 16 + l4 * 4 + r;
        if (grow < M) {
          float v = acc[mi][ni][r] + bv;
          if (RESID) v += bf2f(O16[(size_t)grow * DM + gcol]);
          if (RELU2) v = fmaxf(v, 0.f);
          O16[(size_t)grow * DM + gcol] = f2bf(v);
        }
      }
    }
  }
}

// ---------------- gather (r12 structure): fp8 e, half-wave pairs, 4-deep,
// non-temporal e8 stream loads (u64 scalar form) --------
__global__ __launch_bounds__(256) void gather_e8_kernel(
    const unsigned short* __restrict__ h16,
    const int* __restrict__ row_ptr, const int* __restrict__ esrc,
    const unsigned char* __restrict__ e8,
    const float* __restrict__ eps_ptr, int eps_idx,
    unsigned short* __restrict__ out16, int n)
{
  const int tid = threadIdx.x;
  const int lane = tid & 63, wave = tid >> 6;
  const int half = lane >> 5;
  const int c8 = (lane & 31) * 8;
  const float ep1 = 1.0f + eps_ptr[eps_idx];
  const int stride = gridDim.x * 4;

  for (int i = blockIdx.x * 4 + wave; i < n; i += stride) {
    const int beg = row_ptr[i], end = row_ptr[i + 1];
    const int cnt = end - beg;
    float a[8];
    #pragma unroll
    for (int k = 0; k < 8; ++k) a[k] = 0.f;

    const int npair = cnt >> 1;
    int it = 0;
    for (; it + 4 <= npair; it += 4) {
      int pp[4], ss[4];
      #pragma unroll
      for (int j = 0; j < 4; ++j) {
        pp[j] = beg + 2 * (it + j) + half;
        ss[j] = esrc[pp[j]];
      }
      s16x8 hv[4]; unsigned long long ev[4];
      #pragma unroll
      for (int j = 0; j < 4; ++j) {
        hv[j] = *reinterpret_cast<const s16x8*>(&h16[(size_t)ss[j] * DM + c8]);
        ev[j] = __builtin_nontemporal_load(
            reinterpret_cast<const unsigned long long*>(&e8[(size_t)pp[j] * DM + c8]));
      }
      #pragma unroll
      for (int j = 0; j < 4; ++j) {
        float ee[8];
        dec8((unsigned)ev[j], (unsigned)(ev[j] >> 32), ee);
        #pragma unroll
        for (int k = 0; k < 8; ++k)
          a[k] += fmaxf(bf2f((unsigned short)hv[j][k]) + ee[k], 0.f);
      }
    }
    for (; it < npair; ++it) {
      const int p0 = beg + 2 * it + half;
      const int s0 = esrc[p0];
      const s16x8 h0 = *reinterpret_cast<const s16x8*>(&h16[(size_t)s0 * DM + c8]);
      const unsigned long long e0 = __builtin_nontemporal_load(
          reinterpret_cast<const unsigned long long*>(&e8[(size_t)p0 * DM + c8]));
      float ee[8];
      dec8((unsigned)e0, (unsigned)(e0 >> 32), ee);
      #pragma unroll
      for (int k = 0; k < 8; ++k)
        a[k] += fmaxf(bf2f((unsigned short)h0[k]) + ee[k], 0.f);
    }
    if ((cnt & 1) && half == 0) {
      const int p0 = end - 1;
      const int s0 = esrc[p0];
      const s16x8 h0 = *reinterpret_cast<const s16x8*>(&h16[(size_t)s0 * DM + c8]);
      const unsigned long long e0 = __builtin_nontemporal_load(
          reinterpret_cast<const unsigned long long*>(&e8[(size_t)p0 * DM + c8]));
      float ee[8];
      dec8((unsigned)e0, (unsigned)(e0 >> 32), ee);
      #pragma unroll
      for (int k = 0; k < 8; ++k)
        a[k] += fmaxf(bf2f((unsigned short)h0[k]) + ee[k], 0.f);
    }
    // combine the two half-wave accumulators
    #pragma unroll
    for (int k = 0; k < 8; ++k) a[k] += __shfl_xor(a[k], 32, 64);
    if (half == 0) {
      const s16x8 hs = *reinterpret_cast<const s16x8*>(&h16[(size_t)i * DM + c8]);
      s16x8 o;
      #pragma unroll
      for (int k = 0; k < 8; ++k)
        o[k] = (short)f2bf(ep1 * bf2f((unsigned short)hs[k]) + a[k]);
      *reinterpret_cast<s16x8*>(&out16[(size_t)i * DM + c8]) = o;
    }
  }
}

// ---------------- gather fallback: recompute e per edge -------
__global__ __launch_bounds__(256) void gather_rc_kernel(
    const unsigned short* __restrict__ h16,
    const int* __restrict__ row_ptr, const int* __restrict__ esrc,
    const unsigned short* __restrict__ ea16,
    const float* __restrict__ Wee, const float* __restrict__ bee,
    const float* __restrict__ eps_ptr, int eps_idx,
    unsigned short* __restrict__ out16, int n)
{
  const int tid = threadIdx.x;
  const int lane = tid & 63, wave = tid >> 6;
  const int c4 = lane * 4;
  float4 w[16];
  #pragma unroll
  for (int k = 0; k < 16; ++k)
    w[k] = *reinterpret_cast<const float4*>(&Wee[k * DM + c4]);
  const float4 bv = *reinterpret_cast<const float4*>(&bee[c4]);
  const float ep1 = 1.0f + eps_ptr[eps_idx];
  const int stride = gridDim.x * 4;

  for (int i = blockIdx.x * 4 + wave; i < n; i += stride) {
    const int beg = row_ptr[i], end = row_ptr[i + 1];
    float a0 = 0.f, a1 = 0.f, a2 = 0.f, a3 = 0.f;
    for (int p = beg; p < end; ++p) {
      const int s = esrc[p];
      const ushort4 hv = *reinterpret_cast<const ushort4*>(&h16[(size_t)s * DM + c4]);
      const s16x8* eap = reinterpret_cast<const s16x8*>(&ea16[(size_t)p * DE]);
      const s16x8 ew0 = eap[0], ew1 = eap[1];
      float m0 = bf2f(hv.x) + bv.x, m1 = bf2f(hv.y) + bv.y;
      float m2 = bf2f(hv.z) + bv.z, m3 = bf2f(hv.w) + bv.w;
      float ea[16];
      #pragma unroll
      for (int k = 0; k < 8; ++k) {
        ea[k] = bf2f((unsigned short)ew0[k]);
        ea[8 + k] = bf2f((unsigned short)ew1[k]);
      }
      #pragma unroll
      for (int k = 0; k < 16; ++k) {
        m0 += ea[k] * w[k].x; m1 += ea[k] * w[k].y;
        m2 += ea[k] * w[k].z; m3 += ea[k] * w[k].w;
      }
      a0 += fmaxf(m0, 0.f); a1 += fmaxf(m1, 0.f);
      a2 += fmaxf(m2, 0.f); a3 += fmaxf(m3, 0.f);
    }
    const ushort4 hs = *reinterpret_cast<const ushort4*>(&h16[(size_t)i * DM + c4]);
    ushort4 o;
    o.x = f2bf(ep1 * bf2f(hs.x) + a0); o.y = f2bf(ep1 * bf2f(hs.y) + a1);
    o.z = f2bf(ep1 * bf2f(hs.z) + a2); o.w = f2bf(ep1 * bf2f(hs.w) + a3);
    *reinterpret_cast<ushort4*>(&out16[(size_t)i * DM + c4]) = o;
  }
}

// out[M,10] = h16[M,256] @ W[256,10] + b
__global__ __launch_bounds__(256) void head_kernel(
    const unsigned short* __restrict__ h16, const float* __restrict__ W,
    const float* __restrict__ b, float* __restrict__ out, int M)
{
  __shared__ float Ws[DM * DO];
  const int tid = threadIdx.x;
  for (int i = tid; i < DM * DO; i += 256) Ws[i] = W[i];
  __syncthreads();
  const int r = tid >> 4;
  const int c = tid & 15;
  const int row = blockIdx.x * 16 + r;
  if (row < M && c < DO) {
    const unsigned short* hp = &h16[(size_t)row * DM];
    float acc = 0.f;
    #pragma unroll 8
    for (int k = 0; k < DM; ++k) acc += bf2f(hp[k]) * Ws[k * DO + c];
    out[(size_t)row * DO + c] = acc + b[c];
  }
}

}  // namespace

extern "C" void kernel_launch(void* const* d_in, const int* in_sizes, int n_in,
                              void* d_out, int out_size, void* d_ws, size_t ws_size,
                              hipStream_t stream) {
  const float* x     = (const float*)d_in[0];
  const float* eattr = (const float*)d_in[1];
  const int*   eidx  = (const int*)d_in[2];
  const float* W_ne  = (const float*)d_in[3];
  const float* b_ne  = (const float*)d_in[4];
  const float* W_ee  = (const float*)d_in[5];
  const float* b_ee  = (const float*)d_in[6];
  const float* W_pre = (const float*)d_in[7];
  const float* b_pre = (const float*)d_in[8];
  const float* eps_a = (const float*)d_in[9];
  const float* W1_a  = (const float*)d_in[10];
  const float* b1_a  = (const float*)d_in[11];
  const float* W2_a  = (const float*)d_in[12];
  const float* b2_a  = (const float*)d_in[13];
  const float* eps_l = (const float*)d_in[14];
  const float* W1_l  = (const float*)d_in[15];
  const float* b1_l  = (const float*)d_in[16];
  const float* W2_l  = (const float*)d_in[17];
  const float* b2_l  = (const float*)d_in[18];
  const float* W_h   = (const float*)d_in[19];
  const float* b_h   = (const float*)d_in[20];

  const int* src = eidx;
  const int* dst = eidx + NE;

  // workspace layout (e8 LAST; fallback path needs none of it)
  char* wp = (char*)d_ws;
  unsigned short* h16   = (unsigned short*)wp; wp += (size_t)NN * DM * 2;
  unsigned short* agg16 = (unsigned short*)wp; wp += (size_t)NN * DM * 2;
  unsigned short* ea16  = (unsigned short*)wp; wp += (size_t)NE * DE * 2;
  unsigned short* wt    = (unsigned short*)wp; wp += WTOTAL * 2;
  unsigned short* wtee  = (unsigned short*)wp; wp += (size_t)DM * DE * 2;
  int* esrc    = (int*)wp;                     wp += (size_t)NE * 4;
  int* counts  = (int*)wp;                     wp += (size_t)NN * 4;
  int* row_ptr = (int*)wp;                     wp += (size_t)(NN + 1) * 4;
  int* cursor  = (int*)wp;                     wp += (size_t)NN * 4;
  wp = (char*)(((uintptr_t)wp + 15) & ~(uintptr_t)15);
  unsigned char* e8 = (unsigned char*)wp;
  const size_t need_e8 = (size_t)(wp - (char*)d_ws) + (size_t)NE * DM;
  const bool use_e8 = ws_size >= need_e8;

  // ---- CSR build ----
  zero_kernel<<<(NN + 255) / 256, 256, 0, stream>>>(counts, NN);
  hist_kernel<<<(NE + 255) / 256, 256, 0, stream>>>(dst, counts, NE);
  scan_kernel<<<1, 1024, 0, stream>>>(counts, row_ptr, cursor, NN);
  scatter_kernel<<<(NE + 255) / 256, 256, 0, stream>>>(
      src, dst, eattr, cursor, esrc, ea16, NE);

  // ---- weight preprocessing (main weights + W_ee in one launch) ----
  convertW_kernel<<<dim3(16, 13), 256, 0, stream>>>(
      W_ne, W_pre, W1_a, W2_a, W1_l, W2_l, W_ee, wt, wtee);

  // ---- edge encoder (layer-invariant), once ----
  if (use_e8)
    eenc_kernel<<<dim3(NE / 128, 2), 256, 0, stream>>>(ea16, wtee, b_ee, e8);

  const int mlpgrid = (NN + 63) / 64;

  // encoder + pre-MP fused: h16 = relu((x @ W_ne + b_ne) @ W_pre + b_pre)
  mlp_kernel<false, true, false, false><<<mlpgrid, 512, 0, stream>>>(
      x, nullptr, wt + woff(0), b_ne, wt + woff(1), b_pre, h16, NN, DI);

  for (int layer = 0; layer < 5; ++layer) {
    const float* eps; int ei; const float *b1, *b2; size_t o1, o2;
    if (layer == 0) {
      eps = eps_a; ei = 0; b1 = b1_a; b2 = b2_a;
      o1 = woff(2); o2 = woff(3);
    } else {
      const int i = layer - 1;
      eps = eps_l; ei = i;
      b1 = b1_l + (size_t)i * DM; b2 = b2_l + (size_t)i * DM;
      o1 = woff(4 + i); o2 = woff(8 + i);
    }
    if (use_e8)
      gather_e8_kernel<<<5000, 256, 0, stream>>>(
          h16, row_ptr, esrc, e8, eps, ei, agg16, NN);
    else
      gather_rc_kernel<<<1280, 256, 0, stream>>>(
          h16, row_ptr, esrc, ea16, W_ee, b_ee, eps, ei, agg16, NN);
    // h16 = [h16 +] relu(agg16 @ W1 + b1) @ W2 + b2
    if (layer == 0)
      mlp_kernel<true, false, false, true><<<mlpgrid, 512, 0, stream>>>(
          nullptr, agg16, wt + o1, b1, wt + o2, b2, h16, NN, DM);
    else
      mlp_kernel<true, false, true, true><<<mlpgrid, 512, 0, stream>>>(
          nullptr, agg16, wt + o1, b1, wt + o2, b2, h16, NN, DM);
  }

  head_kernel<<<(NN + 15) / 16, 256, 0, stream>>>(h16, W_h, b_h, (float*)d_out, NN);
}

// Round 19
// 443.568 us; speedup vs baseline: 1.0558x; 1.0558x over previous
//
#include <hip/hip_runtime.h>
#include <hip/hip_bf16.h>

namespace {

constexpr int NN = 20000;   // nodes
constexpr int NE = 320000;  // edges
constexpr int DI = 64;      // input node dim
constexpr int DE = 16;      // edge attr dim
constexpr int DM = 256;     // hidden dim
constexpr int DO = 10;      // out dim

__host__ __device__ constexpr size_t woff(int m) {
  return m == 0 ? 0 : (size_t)16384 + (size_t)(m - 1) * 65536;
}
constexpr size_t WTOTAL = 16384 + 11 * 65536;

typedef __attribute__((ext_vector_type(8))) short s16x8;
typedef __attribute__((ext_vector_type(4))) float f32x4;
typedef __attribute__((ext_vector_type(2))) float f32x2;

#if __has_builtin(__builtin_amdgcn_cvt_pk_f32_fp8) && __has_builtin(__builtin_amdgcn_cvt_pk_fp8_f32)
#define HWFP8 1
#else
#define HWFP8 0
#endif

__device__ inline unsigned short f2bf(float x) {
  union { float f; unsigned u; } c; c.f = x;
  unsigned r = (c.u + 0x7FFFu + ((c.u >> 16) & 1u)) >> 16;
  return (unsigned short)r;
}
__device__ inline float bf2f(unsigned short h) {
  union { unsigned u; float f; } c; c.u = ((unsigned)h) << 16;
  return c.f;
}
__device__ inline float asf(unsigned u) {
  union { unsigned u; float f; } c; c.u = u;
  return c.f;
}

#if !HWFP8
// software pair: extended-normal-at-e0 encode + matching decode
__device__ inline unsigned char f2e4m3(float x) {
  union { float f; unsigned u; } c; c.f = x;
  const unsigned s = (c.u >> 24) & 0x80u;
  c.u &= 0x7FFFFFFFu;
  c.f = fminf(c.f, 448.f);
  const unsigned b = c.u + 0x7FFFFu + ((c.u >> 20) & 1u);
  unsigned r = (b >> 20) - 960u;
  r = (c.f >= 0.0078125f) ? r : 0u;
  return (unsigned char)(s | r);
}
__device__ inline float e4m32f(unsigned u) {
  unsigned b = ((u & 0x80u) << 24) | (((u & 0x7Fu) << 20) + 0x3C000000u);
  if ((u & 0x7Fu) == 0) b &= 0x80000000u;
  union { unsigned u; float f; } c; c.u = b;
  return c.f;
}
#endif

// decode 8 fp8 -> 4 packed f32x2 pairs (channel pairs {2k,2k+1})
__device__ inline void dec8p(uint2 ev, f32x2* e) {
#if HWFP8
  e[0] = __builtin_amdgcn_cvt_pk_f32_fp8((int)ev.x, false);
  e[1] = __builtin_amdgcn_cvt_pk_f32_fp8((int)ev.x, true);
  e[2] = __builtin_amdgcn_cvt_pk_f32_fp8((int)ev.y, false);
  e[3] = __builtin_amdgcn_cvt_pk_f32_fp8((int)ev.y, true);
#else
  e[0] = (f32x2){e4m32f(ev.x & 255u), e4m32f((ev.x >> 8) & 255u)};
  e[1] = (f32x2){e4m32f((ev.x >> 16) & 255u), e4m32f((ev.x >> 24) & 255u)};
  e[2] = (f32x2){e4m32f(ev.y & 255u), e4m32f((ev.y >> 8) & 255u)};
  e[3] = (f32x2){e4m32f((ev.y >> 16) & 255u), e4m32f((ev.y >> 24) & 255u)};
#endif
}

// ---------------- CSR build (counting sort by dst) ----------------

__global__ __launch_bounds__(256) void zero_kernel(int* __restrict__ p, int n) {
  const int j = blockIdx.x * 256 + threadIdx.x;
  if (j < n) p[j] = 0;
}

__global__ __launch_bounds__(256) void hist_kernel(
    const int* __restrict__ dst, int* __restrict__ counts, int E)
{
  const int j = blockIdx.x * 256 + threadIdx.x;
  if (j < E) atomicAdd(&counts[dst[j]], 1);
}

__global__ __launch_bounds__(1024) void scan_kernel(
    const int* __restrict__ counts, int* __restrict__ row_ptr,
    int* __restrict__ cursor, int n)
{
  __shared__ int partial[1024];
  const int t = threadIdx.x;
  const int chunk = (n + 1023) / 1024;
  const int beg = t * chunk;
  const int end = min(beg + chunk, n);
  int s = 0;
  for (int i = beg; i < end; ++i) s += counts[i];
  partial[t] = s;
  __syncthreads();
  for (int off = 1; off < 1024; off <<= 1) {
    const int v = (t >= off) ? partial[t - off] : 0;
    __syncthreads();
    partial[t] += v;
    __syncthreads();
  }
  int base = (t == 0) ? 0 : partial[t - 1];
  for (int i = beg; i < end; ++i) {
    const int c = counts[i];
    row_ptr[i] = base;
    cursor[i] = base;
    base += c;
  }
  if (t == 1023) row_ptr[n] = partial[1023];
}

__global__ __launch_bounds__(256) void scatter_kernel(
    const int* __restrict__ src, const int* __restrict__ dst,
    const float* __restrict__ eattr, int* __restrict__ cursor,
    int* __restrict__ esrc, unsigned short* __restrict__ ea16, int E)
{
  const int j = blockIdx.x * 256 + threadIdx.x;
  if (j < E) {
    const int p = atomicAdd(&cursor[dst[j]], 1);
    esrc[p] = src[j];
    const float4* ep = reinterpret_cast<const float4*>(&eattr[(size_t)j * DE]);
    const float4 e0 = ep[0], e1 = ep[1], e2 = ep[2], e3 = ep[3];
    const float ea[16] = {e0.x, e0.y, e0.z, e0.w, e1.x, e1.y, e1.z, e1.w,
                          e2.x, e2.y, e2.z, e2.w, e3.x, e3.y, e3.z, e3.w};
    s16x8 v0, v1;
    #pragma unroll
    for (int k = 0; k < 8; ++k) {
      v0[k] = (short)f2bf(ea[k]);
      v1[k] = (short)f2bf(ea[8 + k]);
    }
    s16x8* op = reinterpret_cast<s16x8*>(&ea16[(size_t)p * DE]);
    op[0] = v0; op[1] = v1;
  }
}

// ---------------- weight preprocessing: transpose + bf16 ----------------
// mat 0..11 = main weights; mat 12 = W_ee (16x256 -> 256x16)
__global__ __launch_bounds__(256) void convertW_kernel(
    const float* __restrict__ W_ne, const float* __restrict__ W_pre,
    const float* __restrict__ W1_a, const float* __restrict__ W2_a,
    const float* __restrict__ W1_l, const float* __restrict__ W2_l,
    const float* __restrict__ Wee,
    unsigned short* __restrict__ hi, unsigned short* __restrict__ Wt16)
{
  const int mat = blockIdx.y;
  if (mat == 12) {
    if (blockIdx.x == 0) {
      const int n = threadIdx.x;
      #pragma unroll
      for (int k = 0; k < DE; ++k)
        Wt16[n * DE + k] = f2bf(Wee[k * DM + n]);
    }
    return;
  }
  const float* src;
  int K = 256;
  if (mat == 0)      { src = W_ne;  K = 64; }
  else if (mat == 1) { src = W_pre; }
  else if (mat == 2) { src = W1_a; }
  else if (mat == 3) { src = W2_a; }
  else if (mat < 8)  { src = W1_l + (size_t)(mat - 4) * 65536; }
  else               { src = W2_l + (size_t)(mat - 8) * 65536; }
  const size_t off = woff(mat);

  const int ntiles = (K >> 6) * 4;
  const int t = blockIdx.x;
  if (t >= ntiles) return;
  const int tk = t % (K >> 6);
  const int tn = t / (K >> 6);

  __shared__ float tile[64][65];
  const int tid = threadIdx.x;
  const int c = tid & 63;
  const int rg = tid >> 6;
  for (int i = 0; i < 16; ++i) {
    const int r = rg + i * 4;
    tile[r][c] = src[(size_t)(tk * 64 + r) * 256 + tn * 64 + c];
  }
  __syncthreads();
  const int k = tk * 64 + c;
  for (int i = 0; i < 16; ++i) {
    const int nn = rg + i * 4;
    const int n = tn * 64 + nn;
    hi[off + (size_t)n * K + k] = f2bf(tile[c][nn]);
  }
}

// ---------------- edge encoder: e8[p] = e4m3(ea16[p] @ W_ee + b_ee) -----
__global__ __launch_bounds__(256) void eenc_kernel(
    const unsigned short* __restrict__ ea16, const unsigned short* __restrict__ Wt16,
    const float* __restrict__ bee, unsigned char* __restrict__ e8)
{
  __shared__ unsigned stage_dw[128][36];  // 144 B/row
  const int tid = threadIdx.x;
  const int lane = tid & 63, wid = tid >> 6;
  const int l15 = lane & 15, l4 = lane >> 4;
  const int eBase0 = blockIdx.x * 128;
  const int eBase = eBase0 + wid * 32;
  const int colBase = blockIdx.y * 128;
  const s16x8 zz = {0, 0, 0, 0, 0, 0, 0, 0};

  s16x8 ah[2];
  #pragma unroll
  for (int mi = 0; mi < 2; ++mi) {
    const int edge = eBase + mi * 16 + l15;
    ah[mi] = (l4 < 2)
        ? *reinterpret_cast<const s16x8*>(&ea16[(size_t)edge * DE + l4 * 8]) : zz;
  }
  s16x8 bh[8];
  #pragma unroll
  for (int ni = 0; ni < 8; ++ni) {
    const int col = colBase + ni * 16 + l15;
    bh[ni] = (l4 < 2)
        ? *reinterpret_cast<const s16x8*>(&Wt16[col * DE + l4 * 8]) : zz;
  }
  f32x4 acc2[8][2];
  #pragma unroll
  for (int ni = 0; ni < 8; ++ni)
    #pragma unroll
    for (int mi = 0; mi < 2; ++mi)
      acc2[ni][mi] = (f32x4){0.f, 0.f, 0.f, 0.f};
  #pragma unroll
  for (int ni = 0; ni < 8; ++ni)
    #pragma unroll
    for (int mi = 0; mi < 2; ++mi)
      acc2[ni][mi] = __builtin_amdgcn_mfma_f32_16x16x32_bf16(bh[ni], ah[mi], acc2[ni][mi], 0, 0, 0);

  #pragma unroll
  for (int ni = 0; ni < 8; ++ni) {
    const float4 bv = *reinterpret_cast<const float4*>(&bee[colBase + ni * 16 + l4 * 4]);
    #pragma unroll
    for (int mi = 0; mi < 2; ++mi) {
      const int erow = wid * 32 + mi * 16 + l15;
      const float v0 = acc2[ni][mi][0] + bv.x;
      const float v1 = acc2[ni][mi][1] + bv.y;
      const float v2 = acc2[ni][mi][2] + bv.z;
      const float v3 = acc2[ni][mi][3] + bv.w;
#if HWFP8
      unsigned dw = 0;
      dw = (unsigned)__builtin_amdgcn_cvt_pk_fp8_f32(v0, v1, (int)dw, false);
      dw = (unsigned)__builtin_amdgcn_cvt_pk_fp8_f32(v2, v3, (int)dw, true);
      stage_dw[erow][ni * 4 + l4] = dw;
#else
      unsigned char* bp = reinterpret_cast<unsigned char*>(&stage_dw[erow][0]);
      const int col0 = ni * 16 + l4 * 4;
      bp[col0 + 0] = f2e4m3(v0); bp[col0 + 1] = f2e4m3(v1);
      bp[col0 + 2] = f2e4m3(v2); bp[col0 + 3] = f2e4m3(v3);
#endif
    }
  }
  __syncthreads();
  const unsigned char* sb = reinterpret_cast<const unsigned char*>(stage_dw);
  #pragma unroll
  for (int it = 0; it < 4; ++it) {
    const int idx = tid + it * 256;
    const int e = idx >> 3, cc = idx & 7;
    const s16x8 v = *reinterpret_cast<const s16x8*>(sb + (size_t)e * 144 + cc * 16);
    *reinterpret_cast<s16x8*>(&e8[(size_t)(eBase0 + e) * DM + colBase + cc * 16]) = v;
  }
}

// ---------------- fused MLP: BM=64, 512 threads, bf16 weights --------
template<bool RELU1, bool RELU2, bool RESID, bool ABF16>
__global__ __launch_bounds__(512) void mlp_kernel(
    const float* __restrict__ Af, const unsigned short* __restrict__ Ab,
    const unsigned short* __restrict__ B1, const float* __restrict__ b1,
    const unsigned short* __restrict__ B2, const float* __restrict__ b2,
    unsigned short* __restrict__ O16, int M, int K1)
{
  __shared__ unsigned short Tst[64 * 256];
  __shared__ unsigned short Ws[256 * 32];
  unsigned short* Ast = Tst;

  const int tid = threadIdx.x;
  const int lane = tid & 63, wid = tid >> 6;
  const int wr = wid >> 2, wc = wid & 3;
  const int l15 = lane & 15, l4 = lane >> 4;
  const int rowBase = blockIdx.x * 64;
  const int colW = wc * 64;

  f32x4 acc[2][4];
  #pragma unroll
  for (int i = 0; i < 2; ++i)
    #pragma unroll
    for (int j = 0; j < 4; ++j) acc[i][j] = (f32x4){0.f, 0.f, 0.f, 0.f};

  const int nk1 = K1 >> 5;
  for (int ks = 0; ks < nk1; ++ks) {
    if (tid < 256) {
      const int row = tid >> 2, kc = tid & 3;
      const int grow = rowBase + row;
      const int chunk = row * 4 + (kc ^ (row & 3));
      s16x8 v = {0, 0, 0, 0, 0, 0, 0, 0};
      if (grow < M) {
        if (ABF16) {
          v = *reinterpret_cast<const s16x8*>(&Ab[(size_t)grow * K1 + ks * 32 + kc * 8]);
        } else {
          const float* p = Af + (size_t)grow * K1 + ks * 32 + kc * 8;
          const float4 v0 = *reinterpret_cast<const float4*>(p);
          const float4 v1 = *reinterpret_cast<const float4*>(p + 4);
          const float xs[8] = {v0.x, v0.y, v0.z, v0.w, v1.x, v1.y, v1.z, v1.w};
          #pragma unroll
          for (int j = 0; j < 8; ++j) v[j] = (short)f2bf(xs[j]);
        }
      }
      ((s16x8*)Ast)[chunk] = v;
    }
    #pragma unroll
    for (int i = 0; i < 2; ++i) {
      const int u = tid + i * 512;
      const int c = u >> 2, kc = u & 3;
      const int chunk = c * 4 + (kc ^ (c & 3));
      ((s16x8*)Ws)[chunk] = *reinterpret_cast<const s16x8*>(B1 + (size_t)c * K1 + ks * 32 + kc * 8);
    }
    __syncthreads();
    s16x8 a[2], bw[4];
    #pragma unroll
    for (int mi = 0; mi < 2; ++mi) {
      const int r = wr * 32 + mi * 16 + l15;
      a[mi] = ((const s16x8*)Ast)[r * 4 + (l4 ^ (r & 3))];
    }
    #pragma unroll
    for (int ni = 0; ni < 4; ++ni) {
      const int c = colW + ni * 16 + l15;
      bw[ni] = ((const s16x8*)Ws)[c * 4 + (l4 ^ (c & 3))];
    }
    #pragma unroll
    for (int mi = 0; mi < 2; ++mi)
      #pragma unroll
      for (int ni = 0; ni < 4; ++ni)
        acc[mi][ni] = __builtin_amdgcn_mfma_f32_16x16x32_bf16(a[mi], bw[ni], acc[mi][ni], 0, 0, 0);
    __syncthreads();
  }
  #pragma unroll
  for (int ni = 0; ni < 4; ++ni) {
    const int col = colW + ni * 16 + l15;
    const float bv = b1[col];
    #pragma unroll
    for (int mi = 0; mi < 2; ++mi) {
      #pragma unroll
      for (int r = 0; r < 4; ++r) {
        const int row = wr * 32 + mi * 16 + l4 * 4 + r;
        float v = acc[mi][ni][r] + bv;
        if (RELU1) v = fmaxf(v, 0.f);
        const int c32 = col >> 3;
        const int chunk = row * 32 + (c32 ^ (row & 31));
        Tst[chunk * 8 + (col & 7)] = f2bf(v);
        acc[mi][ni][r] = 0.f;
      }
    }
  }
  __syncthreads();

  for (int ks = 0; ks < 8; ++ks) {
    #pragma unroll
    for (int i = 0; i < 2; ++i) {
      const int u = tid + i * 512;
      const int c = u >> 2, kc = u & 3;
      const int chunk = c * 4 + (kc ^ (c & 3));
      ((s16x8*)Ws)[chunk] = *reinterpret_cast<const s16x8*>(B2 + (size_t)c * 256 + ks * 32 + kc * 8);
    }
    __syncthreads();
    s16x8 a[2], bw[4];
    #pragma unroll
    for (int mi = 0; mi < 2; ++mi) {
      const int row = wr * 32 + mi * 16 + l15;
      const int c32 = ks * 4 + l4;
      a[mi] = ((const s16x8*)Tst)[row * 32 + (c32 ^ (row & 31))];
    }
    #pragma unroll
    for (int ni = 0; ni < 4; ++ni) {
      const int c = colW + ni * 16 + l15;
      bw[ni] = ((const s16x8*)Ws)[c * 4 + (l4 ^ (c & 3))];
    }
    #pragma unroll
    for (int mi = 0; mi < 2; ++mi)
      #pragma unroll
      for (int ni = 0; ni < 4; ++ni)
        acc[mi][ni] = __builtin_amdgcn_mfma_f32_16x16x32_bf16(a[mi], bw[ni], acc[mi][ni], 0, 0, 0);
    __syncthreads();
  }
  #pragma unroll
  for (int ni = 0; ni < 4; ++ni) {
    const int gcol = colW + ni * 16 + l15;
    const float bv = b2[gcol];
    #pragma unroll
    for (int mi = 0; mi < 2; ++mi) {
      #pragma unroll
      for (int r = 0; r < 4; ++r) {
        const int grow = rowBase + wr * 32 + mi * 16 + l4 * 4 + r;
        if (grow < M) {
          float v = acc[mi][ni][r] + bv;
          if (RESID) v += bf2f(O16[(size_t)grow * DM + gcol]);
          if (RELU2) v = fmaxf(v, 0.f);
          O16[(size_t)grow * DM + gcol] = f2bf(v);
        }
      }
    }
  }
}

// ---------------- gather (r15 form): fp8 e, half-wave pairs, 4-deep,
// packed f32x2 math --------
__global__ __launch_bounds__(256) void gather_e8_kernel(
    const unsigned short* __restrict__ h16,
    const int* __restrict__ row_ptr, const int* __restrict__ esrc,
    const unsigned char* __restrict__ e8,
    const float* __restrict__ eps_ptr, int eps_idx,
    unsigned short* __restrict__ out16, int n)
{
  const int tid = threadIdx.x;
  const int lane = tid & 63, wave = tid >> 6;
  const int half = lane >> 5;
  const int c8 = (lane & 31) * 8;
  const float ep1 = 1.0f + eps_ptr[eps_idx];
  const int stride = gridDim.x * 4;
  const f32x2 z2 = {0.f, 0.f};

  for (int i = blockIdx.x * 4 + wave; i < n; i += stride) {
    const int beg = row_ptr[i], end = row_ptr[i + 1];
    const int cnt = end - beg;
    f32x2 a2[4];
    #pragma unroll
    for (int k = 0; k < 4; ++k) a2[k] = z2;

    const int npair = cnt >> 1;
    int it = 0;
    for (; it + 4 <= npair; it += 4) {
      int pp[4], ss[4];
      #pragma unroll
      for (int j = 0; j < 4; ++j) {
        pp[j] = beg + 2 * (it + j) + half;
        ss[j] = esrc[pp[j]];
      }
      uint4 hv[4]; uint2 ev[4];
      #pragma unroll
      for (int j = 0; j < 4; ++j) {
        hv[j] = *reinterpret_cast<const uint4*>(&h16[(size_t)ss[j] * DM + c8]);
        ev[j] = *reinterpret_cast<const uint2*>(&e8[(size_t)pp[j] * DM + c8]);
      }
      #pragma unroll
      for (int j = 0; j < 4; ++j) {
        f32x2 ep_[4];
        dec8p(ev[j], ep_);
        const unsigned dws[4] = {hv[j].x, hv[j].y, hv[j].z, hv[j].w};
        #pragma unroll
        for (int k = 0; k < 4; ++k) {
          f32x2 hp;
          hp.x = asf(dws[k] << 16);
          hp.y = asf(dws[k] & 0xFFFF0000u);
          f32x2 m = hp + ep_[k];
          m = __builtin_elementwise_max(m, z2);
          a2[k] += m;
        }
      }
    }
    for (; it < npair; ++it) {
      const int p0 = beg + 2 * it + half;
      const int s0 = esrc[p0];
      const uint4 h0 = *reinterpret_cast<const uint4*>(&h16[(size_t)s0 * DM + c8]);
      const uint2 e0 = *reinterpret_cast<const uint2*>(&e8[(size_t)p0 * DM + c8]);
      f32x2 ep_[4];
      dec8p(e0, ep_);
      const unsigned dws[4] = {h0.x, h0.y, h0.z, h0.w};
      #pragma unroll
      for (int k = 0; k < 4; ++k) {
        f32x2 hp;
        hp.x = asf(dws[k] << 16);
        hp.y = asf(dws[k] & 0xFFFF0000u);
        f32x2 m = hp + ep_[k];
        m = __builtin_elementwise_max(m, z2);
        a2[k] += m;
      }
    }
    if ((cnt & 1) && half == 0) {
      const int p0 = end - 1;
      const int s0 = esrc[p0];
      const uint4 h0 = *reinterpret_cast<const uint4*>(&h16[(size_t)s0 * DM + c8]);
      const uint2 e0 = *reinterpret_cast<const uint2*>(&e8[(size_t)p0 * DM + c8]);
      f32x2 ep_[4];
      dec8p(e0, ep_);
      const unsigned dws[4] = {h0.x, h0.y, h0.z, h0.w};
      #pragma unroll
      for (int k = 0; k < 4; ++k) {
        f32x2 hp;
        hp.x = asf(dws[k] << 16);
        hp.y = asf(dws[k] & 0xFFFF0000u);
        f32x2 m = hp + ep_[k];
        m = __builtin_elementwise_max(m, z2);
        a2[k] += m;
      }
    }
    // combine the two half-wave accumulators
    float a[8] = {a2[0].x, a2[0].y, a2[1].x, a2[1].y,
                  a2[2].x, a2[2].y, a2[3].x, a2[3].y};
    #pragma unroll
    for (int k = 0; k < 8; ++k) a[k] += __shfl_xor(a[k], 32, 64);
    if (half == 0) {
      const s16x8 hs = *reinterpret_cast<const s16x8*>(&h16[(size_t)i * DM + c8]);
      s16x8 o;
      #pragma unroll
      for (int k = 0; k < 8; ++k)
        o[k] = (short)f2bf(ep1 * bf2f((unsigned short)hs[k]) + a[k]);
      *reinterpret_cast<s16x8*>(&out16[(size_t)i * DM + c8]) = o;
    }
  }
}

// ---------------- gather fallback: recompute e per edge -------
__global__ __launch_bounds__(256) void gather_rc_kernel(
    const unsigned short* __restrict__ h16,
    const int* __restrict__ row_ptr, const int* __restrict__ esrc,
    const unsigned short* __restrict__ ea16,
    const float* __restrict__ Wee, const float* __restrict__ bee,
    const float* __restrict__ eps_ptr, int eps_idx,
    unsigned short* __restrict__ out16, int n)
{
  const int tid = threadIdx.x;
  const int lane = tid & 63, wave = tid >> 6;
  const int c4 = lane * 4;
  float4 w[16];
  #pragma unroll
  for (int k = 0; k < 16; ++k)
    w[k] = *reinterpret_cast<const float4*>(&Wee[k * DM + c4]);
  const float4 bv = *reinterpret_cast<const float4*>(&bee[c4]);
  const float ep1 = 1.0f + eps_ptr[eps_idx];
  const int stride = gridDim.x * 4;

  for (int i = blockIdx.x * 4 + wave; i < n; i += stride) {
    const int beg = row_ptr[i], end = row_ptr[i + 1];
    float a0 = 0.f, a1 = 0.f, a2 = 0.f, a3 = 0.f;
    for (int p = beg; p < end; ++p) {
      const int s = esrc[p];
      const ushort4 hv = *reinterpret_cast<const ushort4*>(&h16[(size_t)s * DM + c4]);
      const s16x8* eap = reinterpret_cast<const s16x8*>(&ea16[(size_t)p * DE]);
      const s16x8 ew0 = eap[0], ew1 = eap[1];
      float m0 = bf2f(hv.x) + bv.x, m1 = bf2f(hv.y) + bv.y;
      float m2 = bf2f(hv.z) + bv.z, m3 = bf2f(hv.w) + bv.w;
      float ea[16];
      #pragma unroll
      for (int k = 0; k < 8; ++k) {
        ea[k] = bf2f((unsigned short)ew0[k]);
        ea[8 + k] = bf2f((unsigned short)ew1[k]);
      }
      #pragma unroll
      for (int k = 0; k < 16; ++k) {
        m0 += ea[k] * w[k].x; m1 += ea[k] * w[k].y;
        m2 += ea[k] * w[k].z; m3 += ea[k] * w[k].w;
      }
      a0 += fmaxf(m0, 0.f); a1 += fmaxf(m1, 0.f);
      a2 += fmaxf(m2, 0.f); a3 += fmaxf(m3, 0.f);
    }
    const ushort4 hs = *reinterpret_cast<const ushort4*>(&h16[(size_t)i * DM + c4]);
    ushort4 o;
    o.x = f2bf(ep1 * bf2f(hs.x) + a0); o.y = f2bf(ep1 * bf2f(hs.y) + a1);
    o.z = f2bf(ep1 * bf2f(hs.z) + a2); o.w = f2bf(ep1 * bf2f(hs.w) + a3);
    *reinterpret_cast<ushort4*>(&out16[(size_t)i * DM + c4]) = o;
  }
}

// out[M,10] = h16[M,256] @ W[256,10] + b ; LDS-staged rows
__global__ __launch_bounds__(256) void head_kernel(
    const unsigned short* __restrict__ h16, const float* __restrict__ W,
    const float* __restrict__ b, float* __restrict__ out, int M)
{
  __shared__ float Ws[DM * DO];
  __shared__ unsigned short Hst[16 * DM];  // 8 KB: 16 rows staged
  const int tid = threadIdx.x;
  for (int i = tid; i < DM * DO; i += 256) Ws[i] = W[i];
  const int rowBase = blockIdx.x * 16;
  // coalesced stage: 16 rows x 256 ch x 2B = 8192 B; 256 thr x 2 x 16 B
  #pragma unroll
  for (int i = 0; i < 2; ++i) {
    const int u = tid + i * 256;           // 0..511, 8 bf16 each
    const int r = u >> 5, cc = (u & 31) * 8;
    const int grow = rowBase + r;
    s16x8 v = {0, 0, 0, 0, 0, 0, 0, 0};
    if (grow < M)
      v = *reinterpret_cast<const s16x8*>(&h16[(size_t)grow * DM + cc]);
    *reinterpret_cast<s16x8*>(&Hst[r * DM + cc]) = v;
  }
  __syncthreads();
  const int r = tid >> 4;
  const int c = tid & 15;
  const int row = rowBase + r;
  if (row < M && c < DO) {
    const unsigned short* hp = &Hst[r * DM];
    float acc = 0.f;
    #pragma unroll 8
    for (int k = 0; k < DM; ++k) acc += bf2f(hp[k]) * Ws[k * DO + c];
    out[(size_t)row * DO + c] = acc + b[c];
  }
}

}  // namespace

extern "C" void kernel_launch(void* const* d_in, const int* in_sizes, int n_in,
                              void* d_out, int out_size, void* d_ws, size_t ws_size,
                              hipStream_t stream) {
  const float* x     = (const float*)d_in[0];
  const float* eattr = (const float*)d_in[1];
  const int*   eidx  = (const int*)d_in[2];
  const float* W_ne  = (const float*)d_in[3];
  const float* b_ne  = (const float*)d_in[4];
  const float* W_ee  = (const float*)d_in[5];
  const float* b_ee  = (const float*)d_in[6];
  const float* W_pre = (const float*)d_in[7];
  const float* b_pre = (const float*)d_in[8];
  const float* eps_a = (const float*)d_in[9];
  const float* W1_a  = (const float*)d_in[10];
  const float* b1_a  = (const float*)d_in[11];
  const float* W2_a  = (const float*)d_in[12];
  const float* b2_a  = (const float*)d_in[13];
  const float* eps_l = (const float*)d_in[14];
  const float* W1_l  = (const float*)d_in[15];
  const float* b1_l  = (const float*)d_in[16];
  const float* W2_l  = (const float*)d_in[17];
  const float* b2_l  = (const float*)d_in[18];
  const float* W_h   = (const float*)d_in[19];
  const float* b_h   = (const float*)d_in[20];

  const int* src = eidx;
  const int* dst = eidx + NE;

  // workspace layout (e8 LAST; fallback path needs none of it)
  char* wp = (char*)d_ws;
  unsigned short* h16   = (unsigned short*)wp; wp += (size_t)NN * DM * 2;
  unsigned short* agg16 = (unsigned short*)wp; wp += (size_t)NN * DM * 2;
  unsigned short* ea16  = (unsigned short*)wp; wp += (size_t)NE * DE * 2;
  unsigned short* wt    = (unsigned short*)wp; wp += WTOTAL * 2;
  unsigned short* wtee  = (unsigned short*)wp; wp += (size_t)DM * DE * 2;
  int* esrc    = (int*)wp;                     wp += (size_t)NE * 4;
  int* counts  = (int*)wp;                     wp += (size_t)NN * 4;
  int* row_ptr = (int*)wp;                     wp += (size_t)(NN + 1) * 4;
  int* cursor  = (int*)wp;                     wp += (size_t)NN * 4;
  wp = (char*)(((uintptr_t)wp + 15) & ~(uintptr_t)15);
  unsigned char* e8 = (unsigned char*)wp;
  const size_t need_e8 = (size_t)(wp - (char*)d_ws) + (size_t)NE * DM;
  const bool use_e8 = ws_size >= need_e8;

  // ---- CSR build ----
  zero_kernel<<<(NN + 255) / 256, 256, 0, stream>>>(counts, NN);
  hist_kernel<<<(NE + 255) / 256, 256, 0, stream>>>(dst, counts, NE);
  scan_kernel<<<1, 1024, 0, stream>>>(counts, row_ptr, cursor, NN);
  scatter_kernel<<<(NE + 255) / 256, 256, 0, stream>>>(
      src, dst, eattr, cursor, esrc, ea16, NE);

  // ---- weight preprocessing (main weights + W_ee in one launch) ----
  convertW_kernel<<<dim3(16, 13), 256, 0, stream>>>(
      W_ne, W_pre, W1_a, W2_a, W1_l, W2_l, W_ee, wt, wtee);

  // ---- edge encoder (layer-invariant), once ----
  if (use_e8)
    eenc_kernel<<<dim3(NE / 128, 2), 256, 0, stream>>>(ea16, wtee, b_ee, e8);

  const int mlpgrid = (NN + 63) / 64;

  // encoder + pre-MP fused: h16 = relu((x @ W_ne + b_ne) @ W_pre + b_pre)
  mlp_kernel<false, true, false, false><<<mlpgrid, 512, 0, stream>>>(
      x, nullptr, wt + woff(0), b_ne, wt + woff(1), b_pre, h16, NN, DI);

  for (int layer = 0; layer < 5; ++layer) {
    const float* eps; int ei; const float *b1, *b2; size_t o1, o2;
    if (layer == 0) {
      eps = eps_a; ei = 0; b1 = b1_a; b2 = b2_a;
      o1 = woff(2); o2 = woff(3);
    } else {
      const int i = layer - 1;
      eps = eps_l; ei = i;
      b1 = b1_l + (size_t)i * DM; b2 = b2_l + (size_t)i * DM;
      o1 = woff(4 + i); o2 = woff(8 + i);
    }
    if (use_e8)
      gather_e8_kernel<<<5000, 256, 0, stream>>>(
          h16, row_ptr, esrc, e8, eps, ei, agg16, NN);
    else
      gather_rc_kernel<<<1280, 256, 0, stream>>>(
          h16, row_ptr, esrc, ea16, W_ee, b_ee, eps, ei, agg16, NN);
    // h16 = [h16 +] relu(agg16 @ W1 + b1) @ W2 + b2
    if (layer == 0)
      mlp_kernel<true, false, false, true><<<mlpgrid, 512, 0, stream>>>(
          nullptr, agg16, wt + o1, b1, wt + o2, b2, h16, NN, DM);
    else
      mlp_kernel<true, false, true, true><<<mlpgrid, 512, 0, stream>>>(
          nullptr, agg16, wt + o1, b1, wt + o2, b2, h16, NN, DM);
  }

  head_kernel<<<(NN + 15) / 16, 256, 0, stream>>>(h16, W_h, b_h, (float*)d_out, NN);
}